// Round 10
// baseline (440.868 us; speedup 1.0000x reference)
//
#include <hip/hip_runtime.h>

#define ALPHA_MIN 0.8187307530779818f  // exp(-1/5)
#define ALPHA_MAX 0.9607894391523232f  // exp(-1/25)

typedef _Float16 f16;
typedef _Float16 f16x8 __attribute__((ext_vector_type(8)));
typedef float f32x16 __attribute__((ext_vector_type(16)));

// Fixed problem shape
#define BB_ 32
#define TT_ 2048
#define KK_ 256
#define HH_ 512
#define TC_ 64               // timesteps per chunk
#define NC_ 32               // chunks
#define NB_ 32               // h-cols per block
#define KQ_ 64               // k-quarter staged per round

// async global->LDS, 16 B/lane (dest = uniform base + lane*16)
__device__ __forceinline__ void gll16(const float* g, float* l) {
    __builtin_amdgcn_global_load_lds(
        (const __attribute__((address_space(1))) void*)g,
        (__attribute__((address_space(3))) void*)l, 16, 0, 0);
}

// barrier that waits LDS only (vmcnt NOT drained -> glls stay in flight)
__device__ __forceinline__ void barrier_lds() {
    __builtin_amdgcn_s_waitcnt(0xC07F);   // vmcnt(63) expcnt(7) lgkmcnt(0)
    __builtin_amdgcn_s_barrier();
}

__device__ __forceinline__ void cvt8(const float4 v0, const float4 v1,
                                     f16x8& h, f16x8& l) {
    const float v[8] = {v0.x, v0.y, v0.z, v0.w, v1.x, v1.y, v1.z, v1.w};
#pragma unroll
    for (int j = 0; j < 8; ++j) {
        const f16 hj = (f16)v[j];
        h[j] = hj;
        l[j] = (f16)((v[j] - (float)hj) * 2048.0f);
    }
}

// ============================ fused kernel ==================================
// grid 512 = (nt<<5)|b : XCD = b%8 (nt*32 ≡ 0 mod 8) -> all 16 n-panels of
// batch b share X[b] in one XCD L2 (R5/R9-verified FETCH ~39 MB).
// 2 blocks/CU (the R9 fix: grid 256 capped occupancy at 1 block/CU).
// Block: wave0/1 = GEMM (one 32x32 t x h tile each), wave2 = LIF scan.
// A staged per k-quarter via global_load_lds into wave-PRIVATE rows of a
// 3-buffer rotation -> no cross-wave A dependency, ONE barrier per chunk
// (wx handoff). vmcnt(8) fine-grained waits keep one 8-gll batch always in
// flight. fp16-split GEMM: C = Ah*Bh + 2^-11*(Ah*Bl + Al*Bh), B in regs.
__global__ __launch_bounds__(192, 2) void lif_fused5(
    const float* __restrict__ X,      // (B,T,K)
    const float* __restrict__ W,      // (H,K)
    const float* __restrict__ alpha,  // (H)
    const float* __restrict__ u0,     // (B,H)
    const float* __restrict__ s0,     // (B,H)
    float* __restrict__ out)          // (B,T,H)
{
    __shared__ float Abuf[3][TC_ * KQ_];     // 3 x 16 KB, swizzled 16B groups
    __shared__ float wxbuf[2][TC_ * NB_];    // 2 x 8 KB

    const int b  = blockIdx.x & 31;
    const int nt = blockIdx.x >> 5;
    const int n0 = nt * NB_;

    const int tid  = threadIdx.x;
    const int wv   = tid >> 6;
    const int lane = tid & 63;
    const int fm   = lane & 31;
    const int fq   = lane >> 5;

    if (wv < 2) {
        // ========================= GEMM wave ===============================
        const int mh  = wv;                  // t-half of the 64-row chunk
        const int rlo = lane >> 4;           // row within 4-row gll
        const int sl  = lane & 15;           // 16B slot within 256B row

        const float* xb = X + (size_t)b * TT_ * KK_;

        // stage quarter q (c = q>>2, kq = q&3) into Abuf[q%3], own 32 rows
        auto issue_q = [&](int q) {
            const int c = q >> 2, kq = q & 3, bf = q % 3;
#pragma unroll
            for (int j = 0; j < 8; ++j) {
                const int r0  = mh * 32 + j * 4;
                const int row = r0 + rlo;
                const int g   = sl ^ (row & 15);     // gather-side swizzle
                gll16(xb + (size_t)(c * TC_ + row) * KK_ + kq * KQ_ + g * 4,
                      &Abuf[bf][r0 * KQ_]);
            }
        };
        issue_q(0);
        issue_q(1);

        // B prologue: W[n0+fm][0..256) -> hi/lo f16 frags (128 VGPRs)
        f16x8 bh[16], bl[16];
        {
            const float* wp = W + (size_t)(n0 + fm) * KK_ + fq * 8;
#pragma unroll
            for (int ks = 0; ks < 16; ++ks) {
                float4 v0 = *(const float4*)(wp + ks * 16);
                float4 v1 = *(const float4*)(wp + ks * 16 + 4);
                cvt8(v0, v1, bh[ks], bl[ks]);
            }
        }

        f32x16 accH, accLa, accLb;
#pragma unroll
        for (int e = 0; e < 16; ++e) { accH[e] = 0.0f; accLa[e] = 0.0f; accLb[e] = 0.0f; }

        const int row = mh * 32 + fm;        // this lane's A row
        const int r15 = row & 15;

        for (int c = 0; c < NC_; ++c) {
            barrier_lds();                   // wx[c-1] visible to scan
#pragma unroll
            for (int kq = 0; kq < 4; ++kq) {
                // wait own gll batch for quarter q (leave q+1 in flight)
                if (c < NC_ - 1 || kq < 2)
                    __builtin_amdgcn_s_waitcnt(0x0F78);   // vmcnt(8)
                else
                    __builtin_amdgcn_s_waitcnt(0x0F70);   // vmcnt(0) tail
                __builtin_amdgcn_sched_barrier(0);

                const int q  = c * 4 + kq;
                const float* ab = &Abuf[q % 3][row * KQ_];
#pragma unroll
                for (int ks = 0; ks < 4; ++ks) {
                    const int G  = ks * 4 + fq * 2;
                    const float4 a0 = *(const float4*)&ab[((G    ) ^ r15) * 4];
                    const float4 a1 = *(const float4*)&ab[((G + 1) ^ r15) * 4];
                    f16x8 ah, al;
                    cvt8(a0, a1, ah, al);
                    const int ksg = kq * 4 + ks;
                    accH  = __builtin_amdgcn_mfma_f32_32x32x16_f16(ah, bh[ksg], accH,  0, 0, 0);
                    accLa = __builtin_amdgcn_mfma_f32_32x32x16_f16(ah, bl[ksg], accLa, 0, 0, 0);
                    accLb = __builtin_amdgcn_mfma_f32_32x32x16_f16(al, bh[ksg], accLb, 0, 0, 0);
                }
                if (q + 2 < NC_ * 4) issue_q(q + 2);
            }
            // epilogue: 32x32 tile -> wxbuf[c&1]
            // C/D: col = lane&31, row = (r&3) + 8*(r>>2) + 4*(lane>>5)
            float* wb = &wxbuf[c & 1][0];
#pragma unroll
            for (int r = 0; r < 16; ++r) {
                const int roww = mh * 32 + (r & 3) + 8 * (r >> 2) + 4 * fq;
                wb[roww * NB_ + fm] = accH[r] + (accLa[r] + accLb[r]) * (1.0f / 2048.0f);
                accH[r] = 0.0f; accLa[r] = 0.0f; accLb[r] = 0.0f;
            }
        }
        barrier_lds();                       // final wx handoff
    } else {
        // ========================= scan wave ===============================
        const int hl = lane & 31;            // lanes 32-63 duplicate, no store
        const int h  = n0 + hl;
        const int chain = b * HH_ + h;
        float a = alpha[h];
        a = fminf(fmaxf(a, ALPHA_MIN), ALPHA_MAX);
        const float bbv = 1.0f - a;
        float u = u0[chain];
        float s = s0[chain];
        float* op = out + (size_t)b * TT_ * HH_ + h;
        const bool writer = (lane < 32);

        auto consume = [&](int cc) {
            const float* wb = &wxbuf[cc & 1][0];
            const int tb = cc * TC_;
            for (int t0 = 0; t0 < TC_; t0 += 8) {
                float w[8];
#pragma unroll
                for (int j = 0; j < 8; ++j) w[j] = wb[(t0 + j) * NB_ + hl];
#pragma unroll
                for (int j = 0; j < 8; ++j) {
                    u = fmaf(a, u - s, bbv * w[j]);
                    s = (u > 1.0f) ? 1.0f : 0.0f;
                    if (writer)
                        __builtin_nontemporal_store(s, &op[(size_t)(tb + t0 + j) * HH_]);
                }
            }
        };

        for (int c = 0; c < NC_; ++c) {
            barrier_lds();
            if (c > 0) consume(c - 1);       // overlaps GEMM chunk c
        }
        barrier_lds();
        consume(NC_ - 1);
    }
}

// =================== generic fallback (non-reference shapes) ================
__global__ void gemm_naive(const float* __restrict__ X, const float* __restrict__ W,
                           float* __restrict__ C, int M, int N, int K)
{
    const int idx = blockIdx.x * 256 + threadIdx.x;
    if (idx >= M * N) return;
    const int m = idx / N, n = idx % N;
    float acc = 0.0f;
    for (int k = 0; k < K; ++k) acc = fmaf(X[(size_t)m * K + k], W[(size_t)n * K + k], acc);
    C[idx] = acc;
}

__global__ __launch_bounds__(64) void lif_scan_inplace(
    float* __restrict__ buf, const float* __restrict__ alpha,
    const float* __restrict__ u0, const float* __restrict__ s0, int T, int H)
{
    const int chain = blockIdx.x * 64 + threadIdx.x;
    const int h = chain % H;
    const int b = chain / H;
    float a = alpha[h];
    a = fminf(fmaxf(a, ALPHA_MIN), ALPHA_MAX);
    const float bb = 1.0f - a;
    float u = u0[chain], s = s0[chain];
    float* base = buf + (size_t)b * T * H + h;
    for (int t = 0; t < T; ++t) {
        u = fmaf(a, u - s, bb * base[(size_t)t * H]);
        s = (u > 1.0f) ? 1.0f : 0.0f;
        base[(size_t)t * H] = s;
    }
}

// ---------------- launch ----------------------------------------------------
extern "C" void kernel_launch(void* const* d_in, const int* in_sizes, int n_in,
                              void* d_out, int out_size, void* d_ws, size_t ws_size,
                              hipStream_t stream) {
    const float* x     = (const float*)d_in[0];
    const float* W     = (const float*)d_in[1];
    const float* alpha = (const float*)d_in[2];
    const float* u0    = (const float*)d_in[3];
    const float* s0    = (const float*)d_in[4];
    float* out = (float*)d_out;

    const int H = in_sizes[2];
    const int I = in_sizes[1] / H;
    const int B = in_sizes[3] / H;
    const int T = in_sizes[0] / (B * I);

    if (B == BB_ && T == TT_ && I == KK_ && H == HH_) {
        lif_fused5<<<512, 192, 0, stream>>>(x, W, alpha, u0, s0, out);
    } else {
        const int M = B * T;
        gemm_naive<<<(M * H + 255) / 256, 256, 0, stream>>>(x, W, out, M, H, I);
        lif_scan_inplace<<<(B * H + 63) / 64, 64, 0, stream>>>(out, alpha, u0, s0, T, H);
    }
}